// Round 2
// baseline (266.895 us; speedup 1.0000x reference)
//
#include <hip/hip_runtime.h>
#include <hip/hip_bf16.h>

// Problem: B=4096, C=32, P=H*W=196, ENC=512, ATT=128.
// Inputs/outputs fp32 (per reference dtypes). MFMA via bf16 hi/lo split:
// x = hi + lo  (hi = bf16_rne(x), lo = bf16_rne(x - hi)); A*B approximated by
// Ah*Bh + Ah*Bl + Al*Bh  -> ~2^-16 relative error, fp32 accumulation in MFMA.

typedef __attribute__((ext_vector_type(8))) short short8;
typedef __attribute__((ext_vector_type(8))) __bf16 bf16x8;
typedef __attribute__((ext_vector_type(4))) float floatx4;
typedef __attribute__((ext_vector_type(4))) float float4v;

static __device__ __forceinline__ float bf2f(unsigned short u) {
    union { unsigned int i; float f; } v; v.i = ((unsigned int)u) << 16; return v.f;
}
static __device__ __forceinline__ unsigned short f2bf(float f) {
    union { float f; unsigned int i; } v; v.f = f;
    unsigned int r = v.i + 0x7FFFu + ((v.i >> 16) & 1u);  // RNE
    return (unsigned short)(r >> 16);
}
static __device__ __forceinline__ float fast_tanh(float x) {
    return 1.0f - 2.0f / (1.0f + __expf(2.0f * x));  // saturates correctly at +/-inf
}
// split 8 contiguous fp32 into bf16 hi/lo fragments
static __device__ __forceinline__ void split8(const float* src, bf16x8* hi, bf16x8* lo) {
    short8 h8, l8;
#pragma unroll
    for (int j = 0; j < 8; j++) {
        float x = src[j];
        unsigned short h = f2bf(x);
        h8[j] = (short)h;
        l8[j] = (short)f2bf(x - bf2f(h));
    }
    *hi = __builtin_bit_cast(bf16x8, h8);
    *lo = __builtin_bit_cast(bf16x8, l8);
}

// ---------------------------------------------------------------------------
// k0: pre-split the N-side weights [U_w(128x512); fb_w(32x512)] -> bf16 hi/lo
// ---------------------------------------------------------------------------
__global__ __launch_bounds__(256) void k0_split(
    const float* __restrict__ U_w, const float* __restrict__ fb_w,
    unsigned short* __restrict__ Bhi, unsigned short* __restrict__ Blo)
{
    int i = blockIdx.x * 256 + threadIdx.x;          // 0 .. 81919 (160*512)
    float x = (i < 65536) ? U_w[i] : fb_w[i - 65536];
    unsigned short h = f2bf(x);
    Bhi[i] = h;
    Blo[i] = f2bf(x - bf2f(h));
}

// ---------------------------------------------------------------------------
// k1: U_h = hidden @ U_w^T + (U_b + W_b)   [4096,128] fp32
//     beta = sigmoid(hidden @ fb_w^T + fb_b) [4096,32] fp32
// One wave per 16-row m-tile; N=160; K=512. hi/lo split A on the fly.
// ---------------------------------------------------------------------------
__global__ __launch_bounds__(64) void k1_uh_beta(
    const float* __restrict__ hidden,           // [4096,512] fp32
    const unsigned short* __restrict__ Bhi,     // [160,512] bf16-hi
    const unsigned short* __restrict__ Blo,     // [160,512] bf16-lo
    const float* __restrict__ U_b,              // [128]
    const float* __restrict__ W_b,              // [128]
    const float* __restrict__ fb_b,             // [32]
    float* __restrict__ uh_out,                 // [4096,128]
    float* __restrict__ beta_out)               // [4096,32]
{
    const int lane = threadIdx.x & 63;
    const int quad = lane >> 4, l16 = lane & 15;
    const int mtile = blockIdx.x;               // 0..255
    const int arow = mtile * 16 + l16;

    floatx4 acc[10];
#pragma unroll
    for (int i = 0; i < 10; i++) acc[i] = (floatx4)(0.0f);

    for (int ks = 0; ks < 16; ks++) {
        const int e0 = ks * 32 + quad * 8;
        bf16x8 ah, al;
        split8(hidden + (size_t)arow * 512 + e0, &ah, &al);
#pragma unroll
        for (int n = 0; n < 10; n++) {
            const int col = n * 16 + l16;       // 0..159
            const size_t bo = (size_t)col * 512 + e0;
            bf16x8 bh = *(const bf16x8*)(Bhi + bo);
            bf16x8 bl = *(const bf16x8*)(Blo + bo);
            acc[n] = __builtin_amdgcn_mfma_f32_16x16x32_bf16(ah, bl, acc[n], 0, 0, 0);
            acc[n] = __builtin_amdgcn_mfma_f32_16x16x32_bf16(al, bh, acc[n], 0, 0, 0);
            acc[n] = __builtin_amdgcn_mfma_f32_16x16x32_bf16(ah, bh, acc[n], 0, 0, 0);
        }
    }

    // D layout: col = lane&15, row = quad*4 + r
#pragma unroll
    for (int n = 0; n < 10; n++) {
        const int col = n * 16 + l16;
#pragma unroll
        for (int r = 0; r < 4; r++) {
            const int m = mtile * 16 + quad * 4 + r;
            float v = acc[n][r];
            if (n < 8) {
                uh_out[(size_t)m * 128 + col] = v + U_b[col] + W_b[col];
            } else {
                const int c = col - 128;
                v += fb_b[c];
                beta_out[(size_t)m * 32 + c] = 1.0f / (1.0f + __expf(-v));
            }
        }
    }
}

// ---------------------------------------------------------------------------
// k2: one block (256 thr) per batch element.
//   D[a][p] = W_w[128x32] @ img[32x196]  (hi/lo split, K=32 per mfma)
//   score[p] = sum_a v[a]*tanh(D + uh[a]); softmax over p;
//   context[c] = beta[c] * sum_p img[c][p]*attw[p]
// ---------------------------------------------------------------------------
#define SSTR 198   // LDS row stride (u16 elems): odd-ish pad -> only free 2-way alias

__global__ __launch_bounds__(256) void k2_attn(
    const float* __restrict__ img,   // [4096][32][196] fp32
    const float* __restrict__ W_w,   // [128][32] fp32
    const float* __restrict__ v_w,   // [128] fp32
    const float* __restrict__ uh,    // [4096][128] fp32 (biases folded)
    const float* __restrict__ beta,  // [4096][32] fp32
    float* __restrict__ out)         // [4096*32] context ++ [4096*196] attw
{
    __shared__ __align__(16) unsigned short s_hi[32 * SSTR + 16];
    __shared__ __align__(16) unsigned short s_lo[32 * SSTR + 16];
    __shared__ float s_uhv[256];   // [0,128): uh ; [128,256): v
    __shared__ float s_score[200];
    __shared__ float s_red[8];

    const int tid = threadIdx.x;
    const int b = blockIdx.x;
    const int wave = tid >> 6, lane = tid & 63, quad = lane >> 4, l16 = lane & 15;

    // ---- Phase A: stage img[b] into LDS as bf16 hi/lo (split once) ----
    {
        const float4v* src = (const float4v*)(img + (size_t)b * 6272);
        for (int i = tid; i < 1568; i += 256) {       // 1568 float4 = 6272 floats
            float4v v = src[i];
            const int c = i / 49, p0 = (i % 49) * 4;  // 196 = 4*49, no row-crossing
            const int base = c * SSTR + p0;           // even -> 4B aligned
            unsigned short h0 = f2bf(v[0]), h1 = f2bf(v[1]);
            unsigned short h2 = f2bf(v[2]), h3 = f2bf(v[3]);
            *(ushort2*)&s_hi[base]     = make_ushort2(h0, h1);
            *(ushort2*)&s_hi[base + 2] = make_ushort2(h2, h3);
            *(ushort2*)&s_lo[base]     = make_ushort2(f2bf(v[0] - bf2f(h0)), f2bf(v[1] - bf2f(h1)));
            *(ushort2*)&s_lo[base + 2] = make_ushort2(f2bf(v[2] - bf2f(h2)), f2bf(v[3] - bf2f(h3)));
        }
    }
    if (tid < 64) {   // zero column pads (p=196,197) -> no NaN garbage into mfma
        const int c = tid >> 1, o = 196 + (tid & 1);
        s_hi[c * SSTR + o] = 0; s_lo[c * SSTR + o] = 0;
    }
    if (tid < 16) {   // zero tail pad
        s_hi[32 * SSTR + tid] = 0; s_lo[32 * SSTR + tid] = 0;
    }
    if (tid < 128) {
        s_uhv[tid] = uh[(size_t)b * 128 + tid];
        s_uhv[128 + tid] = v_w[tid];
    }
    if (tid < 200) s_score[tid] = 0.0f;
    __syncthreads();

    // ---- Phase B: D = W_w x img (hi/lo), fused tanh + v-dot -> s_score ----
    const int atile0 = wave * 2, atile1 = wave * 2 + 1;
    bf16x8 a0h, a0l, a1h, a1l;
    split8(W_w + (size_t)(atile0 * 16 + l16) * 32 + quad * 8, &a0h, &a0l);
    split8(W_w + (size_t)(atile1 * 16 + l16) * 32 + quad * 8, &a1h, &a1l);

    for (int pt = 0; pt < 13; pt++) {
        const int p = pt * 16 + l16;
        short8 th, tl;
        const int kbase = quad * 8 * SSTR + p;
#pragma unroll
        for (int j = 0; j < 8; j++) {
            th[j] = (short)s_hi[kbase + j * SSTR];
            tl[j] = (short)s_lo[kbase + j * SSTR];
        }
        bf16x8 bh = __builtin_bit_cast(bf16x8, th);
        bf16x8 bl = __builtin_bit_cast(bf16x8, tl);

        floatx4 z = (floatx4)(0.0f);
        floatx4 d0 = __builtin_amdgcn_mfma_f32_16x16x32_bf16(a0h, bl, z, 0, 0, 0);
        d0 = __builtin_amdgcn_mfma_f32_16x16x32_bf16(a0l, bh, d0, 0, 0, 0);
        d0 = __builtin_amdgcn_mfma_f32_16x16x32_bf16(a0h, bh, d0, 0, 0, 0);
        floatx4 d1 = __builtin_amdgcn_mfma_f32_16x16x32_bf16(a1h, bl, z, 0, 0, 0);
        d1 = __builtin_amdgcn_mfma_f32_16x16x32_bf16(a1l, bh, d1, 0, 0, 0);
        d1 = __builtin_amdgcn_mfma_f32_16x16x32_bf16(a1h, bh, d1, 0, 0, 0);

        float sc = 0.0f;
#pragma unroll
        for (int r = 0; r < 4; r++) {
            const int aa = atile0 * 16 + quad * 4 + r;
            sc += s_uhv[128 + aa] * fast_tanh(d0[r] + s_uhv[aa]);
            const int ab = atile1 * 16 + quad * 4 + r;
            sc += s_uhv[128 + ab] * fast_tanh(d1[r] + s_uhv[ab]);
        }
        sc += __shfl_xor(sc, 16);
        sc += __shfl_xor(sc, 32);
        if (lane < 16 && p < 196) atomicAdd(&s_score[p], sc);
    }
    __syncthreads();

    // ---- Phase C: softmax over 196 positions (v_b cancels) ----
    float x = (tid < 196) ? s_score[tid] : -1e30f;
    float m = x;
#pragma unroll
    for (int off = 32; off > 0; off >>= 1) m = fmaxf(m, __shfl_xor(m, off));
    if (lane == 0) s_red[wave] = m;
    __syncthreads();
    m = fmaxf(fmaxf(s_red[0], s_red[1]), fmaxf(s_red[2], s_red[3]));
    float e = (tid < 196) ? __expf(x - m) : 0.0f;
    float ssum = e;
#pragma unroll
    for (int off = 32; off > 0; off >>= 1) ssum += __shfl_xor(ssum, off);
    if (lane == 0) s_red[4 + wave] = ssum;
    __syncthreads();
    const float tot = s_red[4] + s_red[5] + s_red[6] + s_red[7];
    const float wgt = e / tot;
    if (tid < 196) {
        s_score[tid] = wgt;
        out[131072 + (size_t)b * 196 + tid] = wgt;   // att_weights (fp32)
    }
    __syncthreads();

    // ---- Phase D: context[c] = beta[c] * sum_p img[c][p]*attw[p] ----
    const int c = tid >> 3, sub = tid & 7;
    float acc = 0.0f;
    for (int p = sub; p < 196; p += 8) {
        const int idx = c * SSTR + p;
        acc += (bf2f(s_hi[idx]) + bf2f(s_lo[idx])) * s_score[p];
    }
    acc += __shfl_xor(acc, 1);
    acc += __shfl_xor(acc, 2);
    acc += __shfl_xor(acc, 4);
    if (sub == 0) {
        out[(size_t)b * 32 + c] = acc * beta[(size_t)b * 32 + c];
    }
}

extern "C" void kernel_launch(void* const* d_in, const int* in_sizes, int n_in,
                              void* d_out, int out_size, void* d_ws, size_t ws_size,
                              hipStream_t stream) {
    const float* img    = (const float*)d_in[0]; // [4096,32,196]
    const float* hidden = (const float*)d_in[1]; // [4096,512]
    const float* W_w    = (const float*)d_in[2]; // [128,32]
    const float* W_b    = (const float*)d_in[3]; // [128]
    const float* U_w    = (const float*)d_in[4]; // [128,512]
    const float* U_b    = (const float*)d_in[5]; // [128]
    const float* v_w    = (const float*)d_in[6]; // [128] (shape (1,128))
    // d_in[7] = v_b: cancels in softmax, unused
    const float* fb_w   = (const float*)d_in[8]; // [32,512]
    const float* fb_b   = (const float*)d_in[9]; // [32]
    float* out = (float*)d_out;

    float* uh_ws   = (float*)d_ws;                       // 4096*128 fp32 = 2 MB
    float* beta_ws = uh_ws + 4096 * 128;                 // 4096*32 fp32 = 0.5 MB
    unsigned short* Bhi = (unsigned short*)(beta_ws + 4096 * 32);  // 160*512 u16
    unsigned short* Blo = Bhi + 160 * 512;

    k0_split<<<dim3(320), dim3(256), 0, stream>>>(U_w, fb_w, Bhi, Blo);
    k1_uh_beta<<<dim3(256), dim3(64), 0, stream>>>(hidden, Bhi, Blo, U_b, W_b, fb_b,
                                                   uh_ws, beta_ws);
    k2_attn<<<dim3(4096), dim3(256), 0, stream>>>(img, W_w, v_w, uh_ws, beta_ws, out);
}

// Round 3
// 239.699 us; speedup vs baseline: 1.1135x; 1.1135x over previous
//
#include <hip/hip_runtime.h>
#include <hip/hip_bf16.h>

// B=4096, C=32, P=196, ENC=512, ATT=128. fp32 I/O; MFMA via bf16 hi/lo split
// (Ah*Bh + Ah*Bl + Al*Bh, fp32 accum -> ~2^-16 rel err).
//
// k2 MFMA roles: M=p (13 tiles), N=a (8 tiles), K=c (32 = one mfma K).
//   A-frag: img transposed in LDS [p][c], 16B ds_read_b128 (2-way banks).
//   B-frag: W_w[a][c] contiguous -> pre-split in k0, held in regs.
//   D: col=a(lane&15), row=p(quad*4+r) -> score reduce = 4x shfl over l16.

typedef __attribute__((ext_vector_type(8))) short short8;
typedef __attribute__((ext_vector_type(8))) __bf16 bf16x8;
typedef __attribute__((ext_vector_type(4))) float floatx4;

static __device__ __forceinline__ float bf2f(unsigned short u) {
    union { unsigned int i; float f; } v; v.i = ((unsigned int)u) << 16; return v.f;
}
static __device__ __forceinline__ unsigned short f2bf(float f) {
    union { float f; unsigned int i; } v; v.f = f;
    unsigned int r = v.i + 0x7FFFu + ((v.i >> 16) & 1u);  // RNE
    return (unsigned short)(r >> 16);
}
static __device__ __forceinline__ float fast_tanh(float x) {
    return 1.0f - 2.0f / (1.0f + __expf(2.0f * x));  // saturates at +/-1
}
static __device__ __forceinline__ void split8(const float* src, bf16x8* hi, bf16x8* lo) {
    short8 h8, l8;
#pragma unroll
    for (int j = 0; j < 8; j++) {
        float x = src[j];
        unsigned short h = f2bf(x);
        h8[j] = (short)h;
        l8[j] = (short)f2bf(x - bf2f(h));
    }
    *hi = __builtin_bit_cast(bf16x8, h8);
    *lo = __builtin_bit_cast(bf16x8, l8);
}

// ---------------------------------------------------------------------------
// k0: split U_w(65536) ++ fb_w(16384) -> Bhi/Blo; W_w(4096) -> Whi/Wlo
// ---------------------------------------------------------------------------
__global__ __launch_bounds__(256) void k0_split(
    const float* __restrict__ U_w, const float* __restrict__ fb_w,
    const float* __restrict__ W_w,
    unsigned short* __restrict__ Bhi, unsigned short* __restrict__ Blo,
    unsigned short* __restrict__ Whi, unsigned short* __restrict__ Wlo)
{
    int i = blockIdx.x * 256 + threadIdx.x;  // 0..86015
    float x;
    if (i < 65536) x = U_w[i];
    else if (i < 81920) x = fb_w[i - 65536];
    else x = W_w[i - 81920];
    unsigned short h = f2bf(x);
    unsigned short l = f2bf(x - bf2f(h));
    if (i < 81920) { Bhi[i] = h; Blo[i] = l; }
    else { Whi[i - 81920] = h; Wlo[i - 81920] = l; }
}

// ---------------------------------------------------------------------------
// k1: uh = hidden @ U_w^T + (U_b+W_b); beta = sigmoid(hidden @ fb_w^T + fb_b)
// 256 blocks x 256 thr. Block = one 16-row m-tile; wave w = K slice w*128..+127.
// LDS reduction of 4 partial [16 x 160] tiles.
// ---------------------------------------------------------------------------
__global__ __launch_bounds__(256) void k1_uh_beta(
    const float* __restrict__ hidden,           // [4096,512]
    const unsigned short* __restrict__ Bhi,     // [160,512]
    const unsigned short* __restrict__ Blo,
    const float* __restrict__ U_b, const float* __restrict__ W_b,
    const float* __restrict__ fb_b,
    float* __restrict__ uh_out,                 // [4096,128]
    float* __restrict__ beta_out)               // [4096,32]
{
    __shared__ float s_part[4 * 2560];
    const int tid = threadIdx.x;
    const int wave = tid >> 6, lane = tid & 63, quad = lane >> 4, l16 = lane & 15;
    const int mtile = blockIdx.x;
    const int arow = mtile * 16 + l16;

    floatx4 acc[10];
#pragma unroll
    for (int i = 0; i < 10; i++) acc[i] = (floatx4)(0.0f);

#pragma unroll
    for (int ksi = 0; ksi < 4; ksi++) {
        const int e0 = (wave * 4 + ksi) * 32 + quad * 8;
        bf16x8 ah, al;
        split8(hidden + (size_t)arow * 512 + e0, &ah, &al);
#pragma unroll
        for (int n = 0; n < 10; n++) {
            const size_t bo = (size_t)(n * 16 + l16) * 512 + e0;
            bf16x8 bh = *(const bf16x8*)(Bhi + bo);
            bf16x8 bl = *(const bf16x8*)(Blo + bo);
            acc[n] = __builtin_amdgcn_mfma_f32_16x16x32_bf16(ah, bl, acc[n], 0, 0, 0);
            acc[n] = __builtin_amdgcn_mfma_f32_16x16x32_bf16(al, bh, acc[n], 0, 0, 0);
            acc[n] = __builtin_amdgcn_mfma_f32_16x16x32_bf16(ah, bh, acc[n], 0, 0, 0);
        }
    }
#pragma unroll
    for (int n = 0; n < 10; n++)
#pragma unroll
        for (int r = 0; r < 4; r++)
            s_part[wave * 2560 + (quad * 4 + r) * 160 + n * 16 + l16] = acc[n][r];
    __syncthreads();

#pragma unroll
    for (int j = 0; j < 10; j++) {
        const int i = tid + j * 256;
        float v = s_part[i] + s_part[2560 + i] + s_part[5120 + i] + s_part[7680 + i];
        const int m = mtile * 16 + i / 160, col = i % 160;
        if (col < 128) {
            uh_out[(size_t)m * 128 + col] = v + U_b[col] + W_b[col];
        } else {
            const int c = col - 128;
            beta_out[(size_t)m * 32 + c] = 1.0f / (1.0f + __expf(-(v + fb_b[c])));
        }
    }
}

// ---------------------------------------------------------------------------
// k2: one block (256 thr) per batch.
// ---------------------------------------------------------------------------
#define PSTR 40    // u16 per LDS row: 32 data + 8 pad (80 B -> 16B aligned, ~2-way banks)
#define PROWS 208

__global__ __launch_bounds__(256) void k2_attn(
    const float* __restrict__ img,            // [4096][32][196]
    const unsigned short* __restrict__ Whi,   // [128][32] bf16-hi
    const unsigned short* __restrict__ Wlo,   // [128][32] bf16-lo
    const float* __restrict__ v_w,            // [128]
    const float* __restrict__ uh,             // [4096][128] (biases folded)
    const float* __restrict__ beta,           // [4096][32]
    float* __restrict__ out)
{
    __shared__ __align__(16) unsigned short s_hi[PROWS * PSTR];  // 16640 B
    __shared__ __align__(16) unsigned short s_lo[PROWS * PSTR];
    __shared__ float s_uhv[256];   // [0,128): uh ; [128,256): v
    __shared__ float s_score[200];
    __shared__ float s_red[8];
    __shared__ float s_ctx[4][32];

    const int tid = threadIdx.x;
    const int b = blockIdx.x;
    const int wave = tid >> 6, lane = tid & 63, quad = lane >> 4, l16 = lane & 15;

    // ---- Phase A: transpose-stage img[b] -> LDS [p][c] as bf16 hi/lo ----
    if (tid < 196) {
        float v[32];
#pragma unroll
        for (int c = 0; c < 32; c++)            // coalesced: lanes = consecutive p
            v[c] = img[(size_t)b * 6272 + c * 196 + tid];
        const int base = tid * PSTR;
#pragma unroll
        for (int g = 0; g < 4; g++) {
            short8 h8, l8;
#pragma unroll
            for (int j = 0; j < 8; j++) {
                float x = v[g * 8 + j];
                unsigned short h = f2bf(x);
                h8[j] = (short)h;
                l8[j] = (short)f2bf(x - bf2f(h));
            }
            *(short8*)&s_hi[base + g * 8] = h8;   // 16B aligned (80*p + 16*g)
            *(short8*)&s_lo[base + g * 8] = l8;
        }
    } else {
        // zero pad rows p=196..207 (12 rows x 40 u16), 60 threads x 8 iters
        for (int i = tid - 196; i < 480; i += 60) {
            s_hi[196 * PSTR + i] = 0;
            s_lo[196 * PSTR + i] = 0;
        }
    }
    if (tid < 128) s_uhv[tid] = uh[(size_t)b * 128 + tid];
    else s_uhv[tid] = v_w[tid - 128];

    // B-frags (wave-invariant, L2-hot): lane n=a=nt*16+l16, k=c=quad*8..+7
    bf16x8 bh[8], bl[8];
#pragma unroll
    for (int nt = 0; nt < 8; nt++) {
        const int a = nt * 16 + l16;
        bh[nt] = *(const bf16x8*)(Whi + a * 32 + quad * 8);
        bl[nt] = *(const bf16x8*)(Wlo + a * 32 + quad * 8);
    }
    __syncthreads();

    // ---- Phase B: per p-tile: A-frag 2x ds_read_b128; 8 n-tiles x 3 mfma ----
    for (int mt = wave; mt < 13; mt += 4) {
        const int p_lane = mt * 16 + l16;
        bf16x8 ah = *(const bf16x8*)&s_hi[p_lane * PSTR + quad * 8];
        bf16x8 al = *(const bf16x8*)&s_lo[p_lane * PSTR + quad * 8];
        float sc[4] = {0.f, 0.f, 0.f, 0.f};
#pragma unroll
        for (int nt = 0; nt < 8; nt++) {
            floatx4 d = (floatx4)(0.0f);
            d = __builtin_amdgcn_mfma_f32_16x16x32_bf16(ah, bl[nt], d, 0, 0, 0);
            d = __builtin_amdgcn_mfma_f32_16x16x32_bf16(al, bh[nt], d, 0, 0, 0);
            d = __builtin_amdgcn_mfma_f32_16x16x32_bf16(ah, bh[nt], d, 0, 0, 0);
            const int a = nt * 16 + l16;
            const float va = s_uhv[128 + a], ua = s_uhv[a];
#pragma unroll
            for (int r = 0; r < 4; r++)
                sc[r] += va * fast_tanh(d[r] + ua);
        }
#pragma unroll
        for (int r = 0; r < 4; r++) {
            sc[r] += __shfl_xor(sc[r], 1);
            sc[r] += __shfl_xor(sc[r], 2);
            sc[r] += __shfl_xor(sc[r], 4);
            sc[r] += __shfl_xor(sc[r], 8);
        }
        if (l16 == 0) {
#pragma unroll
            for (int r = 0; r < 4; r++) {
                const int p = mt * 16 + quad * 4 + r;
                if (p < 196) s_score[p] = sc[r];
            }
        }
    }
    __syncthreads();

    // ---- Phase C: softmax over 196 (v_b cancels) ----
    float x = (tid < 196) ? s_score[tid] : -1e30f;
    float m = x;
#pragma unroll
    for (int off = 32; off > 0; off >>= 1) m = fmaxf(m, __shfl_xor(m, off));
    if (lane == 0) s_red[wave] = m;
    __syncthreads();
    m = fmaxf(fmaxf(s_red[0], s_red[1]), fmaxf(s_red[2], s_red[3]));
    float e = (tid < 196) ? __expf(x - m) : 0.0f;
    float ssum = e;
#pragma unroll
    for (int off = 32; off > 0; off >>= 1) ssum += __shfl_xor(ssum, off);
    if (lane == 0) s_red[4 + wave] = ssum;
    __syncthreads();
    const float tot = s_red[4] + s_red[5] + s_red[6] + s_red[7];
    const float wgt = e / tot;
    if (tid < 196) {
        s_score[tid] = wgt;
        out[131072 + (size_t)b * 196 + tid] = wgt;   // att_weights
    }
    __syncthreads();

    // ---- Phase D: context[c] = beta[c] * sum_p img[c][p]*w[p] ----
    {
        const int c = lane & 31;
        const int po = wave * 2 + (lane >> 5);   // 0..7
        float acc = 0.0f;
        for (int j = 0; j < 25; j++) {
            const int p = po + j * 8;
            if (p < 196) {
                const int idx = p * PSTR + c;
                acc += (bf2f(s_hi[idx]) + bf2f(s_lo[idx])) * s_score[p];
            }
        }
        acc += __shfl_xor(acc, 32);
        if ((lane >> 5) == 0) s_ctx[wave][c] = acc;
    }
    __syncthreads();
    if (tid < 32) {
        const float v = s_ctx[0][tid] + s_ctx[1][tid] + s_ctx[2][tid] + s_ctx[3][tid];
        out[(size_t)b * 32 + tid] = v * beta[(size_t)b * 32 + tid];
    }
}

extern "C" void kernel_launch(void* const* d_in, const int* in_sizes, int n_in,
                              void* d_out, int out_size, void* d_ws, size_t ws_size,
                              hipStream_t stream) {
    const float* img    = (const float*)d_in[0];
    const float* hidden = (const float*)d_in[1];
    const float* W_w    = (const float*)d_in[2];
    const float* W_b    = (const float*)d_in[3];
    const float* U_w    = (const float*)d_in[4];
    const float* U_b    = (const float*)d_in[5];
    const float* v_w    = (const float*)d_in[6];
    // d_in[7] = v_b: cancels in softmax
    const float* fb_w   = (const float*)d_in[8];
    const float* fb_b   = (const float*)d_in[9];
    float* out = (float*)d_out;

    float* uh_ws   = (float*)d_ws;                     // 4096*128
    float* beta_ws = uh_ws + 4096 * 128;               // 4096*32
    unsigned short* Bhi = (unsigned short*)(beta_ws + 4096 * 32);  // 81920
    unsigned short* Blo = Bhi + 81920;
    unsigned short* Whi = Blo + 81920;                 // 4096
    unsigned short* Wlo = Whi + 4096;

    k0_split<<<dim3(336), dim3(256), 0, stream>>>(U_w, fb_w, W_w, Bhi, Blo, Whi, Wlo);
    k1_uh_beta<<<dim3(256), dim3(256), 0, stream>>>(hidden, Bhi, Blo, U_b, W_b, fb_b,
                                                    uh_ws, beta_ws);
    k2_attn<<<dim3(4096), dim3(256), 0, stream>>>(img, Whi, Wlo, v_w, uh_ws, beta_ws, out);
}

// Round 4
// 211.705 us; speedup vs baseline: 1.2607x; 1.1322x over previous
//
#include <hip/hip_runtime.h>
#include <hip/hip_bf16.h>

// B=4096, C=32, P=196, ENC=512, ATT=128. fp32 I/O.
// MFMA via bf16 hi/lo split (Ah*Bh + Ah*Bl + Al*Bh, fp32 accum, ~2^-16 rel).
// R4 changes: rcp-based tanh/sigmoid (no IEEE div), v_perm truncation split,
// fp32 img in LDS, hoisted uh/v regs, launch_bounds(256,4) to stop W-frag
// reload, split-K k1 (ws_size-gated) + k1b reduce.

typedef __attribute__((ext_vector_type(8))) short short8;
typedef __attribute__((ext_vector_type(8))) __bf16 bf16x8;
typedef __attribute__((ext_vector_type(4))) float floatx4;
typedef __attribute__((ext_vector_type(4))) unsigned int uint4v;

static __device__ __forceinline__ float bf2f(unsigned short u) {
    union { unsigned int i; float f; } v; v.i = ((unsigned int)u) << 16; return v.f;
}
static __device__ __forceinline__ unsigned short f2bf(float f) {
    union { float f; unsigned int i; } v; v.f = f;
    unsigned int r = v.i + 0x7FFFu + ((v.i >> 16) & 1u);  // RNE
    return (unsigned short)(r >> 16);
}
// tanh(x) = 1 - 2/(1+e^{2x}); rcp instead of IEEE div (saves ~10 VALU/call).
static __device__ __forceinline__ float tanh_rcp(float x) {
    float e = __expf(2.0f * x);                       // v_mul + v_exp
    float r = __builtin_amdgcn_rcpf(1.0f + e);        // v_add + v_rcp
    return __builtin_fmaf(-2.0f, r, 1.0f);            // v_fma
}
static __device__ __forceinline__ float sigmoid_rcp(float x) {
    return __builtin_amdgcn_rcpf(1.0f + __expf(-x));
}
// Truncation hi/lo split of 8 contiguous fp32 (16B-aligned): hi = top16 bits,
// lo = bf16-trunc(x - hi) (sub exact). Combined err ~2^-16 * |x|.
static __device__ __forceinline__ void split_trunc8(const float* src, bf16x8* hi, bf16x8* lo) {
    uint4v u0 = *(const uint4v*)src;
    uint4v u1 = *(const uint4v*)(src + 4);
    unsigned int fb[8], lb[8];
#pragma unroll
    for (int j = 0; j < 4; j++) { fb[j] = u0[j]; fb[4 + j] = u1[j]; }
#pragma unroll
    for (int k = 0; k < 8; k++) {
        float x = __uint_as_float(fb[k]);
        float h = __uint_as_float(fb[k] & 0xFFFF0000u);
        lb[k] = __float_as_uint(x - h);               // exact
    }
    uint4v hp, lp;
#pragma unroll
    for (int j = 0; j < 4; j++) {
        hp[j] = __builtin_amdgcn_perm(fb[2 * j + 1], fb[2 * j], 0x07060302u);
        lp[j] = __builtin_amdgcn_perm(lb[2 * j + 1], lb[2 * j], 0x07060302u);
    }
    *hi = __builtin_bit_cast(bf16x8, hp);
    *lo = __builtin_bit_cast(bf16x8, lp);
}

// ---------------------------------------------------------------------------
// k0: RNE-split U_w(65536) ++ fb_w(16384) -> Bhi/Blo; W_w(4096) -> Whi/Wlo
// ---------------------------------------------------------------------------
__global__ __launch_bounds__(256) void k0_split(
    const float* __restrict__ U_w, const float* __restrict__ fb_w,
    const float* __restrict__ W_w,
    unsigned short* __restrict__ Bhi, unsigned short* __restrict__ Blo,
    unsigned short* __restrict__ Whi, unsigned short* __restrict__ Wlo)
{
    int i = blockIdx.x * 256 + threadIdx.x;  // 0..86015
    float x;
    if (i < 65536) x = U_w[i];
    else if (i < 81920) x = fb_w[i - 65536];
    else x = W_w[i - 81920];
    unsigned short h = f2bf(x);
    unsigned short l = f2bf(x - bf2f(h));
    if (i < 81920) { Bhi[i] = h; Blo[i] = l; }
    else { Whi[i - 81920] = h; Wlo[i - 81920] = l; }
}

// ---------------------------------------------------------------------------
// k1: partial GEMM  [hidden @ [U_w;fb_w]^T]  with split-K.
// grid = 256*nsplit blocks; block = (mtile, kslice of 512/nsplit).
// 4 waves split the block's K range; LDS-reduce -> partial[bid][2560]
// (or direct epilogue when nsplit==1 && direct).
// ---------------------------------------------------------------------------
__global__ __launch_bounds__(256) void k1_gemm(
    const float* __restrict__ hidden,           // [4096,512]
    const unsigned short* __restrict__ Bhi,     // [160,512]
    const unsigned short* __restrict__ Blo,
    const float* __restrict__ U_b, const float* __restrict__ W_b,
    const float* __restrict__ fb_b,
    float* __restrict__ uh_out, float* __restrict__ beta_out,
    float* __restrict__ partial, int nsplit, int direct)
{
    __shared__ float s_part[4 * 2560];
    const int tid = threadIdx.x;
    const int wave = tid >> 6, lane = tid & 63, quad = lane >> 4, l16 = lane & 15;
    const int mtile = blockIdx.x / nsplit;
    const int kblock = 512 / nsplit;                 // 512/256/128
    const int ks0 = (blockIdx.x % nsplit) * kblock + wave * (kblock >> 2);
    const int ksteps = kblock >> 7;                  // k-steps of 32 per wave: 4/2/1
    const int arow = mtile * 16 + l16;

    floatx4 acc[10];
#pragma unroll
    for (int i = 0; i < 10; i++) acc[i] = (floatx4)(0.0f);

    for (int ksi = 0; ksi < ksteps; ksi++) {
        const int e0 = ks0 + ksi * 32 + quad * 8;
        bf16x8 ah, al;
        split_trunc8(hidden + (size_t)arow * 512 + e0, &ah, &al);
#pragma unroll
        for (int n = 0; n < 10; n++) {
            const size_t bo = (size_t)(n * 16 + l16) * 512 + e0;
            bf16x8 bh = *(const bf16x8*)(Bhi + bo);
            bf16x8 bl = *(const bf16x8*)(Blo + bo);
            acc[n] = __builtin_amdgcn_mfma_f32_16x16x32_bf16(ah, bl, acc[n], 0, 0, 0);
            acc[n] = __builtin_amdgcn_mfma_f32_16x16x32_bf16(al, bh, acc[n], 0, 0, 0);
            acc[n] = __builtin_amdgcn_mfma_f32_16x16x32_bf16(ah, bh, acc[n], 0, 0, 0);
        }
    }
#pragma unroll
    for (int n = 0; n < 10; n++)
#pragma unroll
        for (int r = 0; r < 4; r++)
            s_part[wave * 2560 + (quad * 4 + r) * 160 + n * 16 + l16] = acc[n][r];
    __syncthreads();

#pragma unroll
    for (int j = 0; j < 10; j++) {
        const int i = tid + j * 256;
        float v = s_part[i] + s_part[2560 + i] + s_part[5120 + i] + s_part[7680 + i];
        if (direct) {
            const int m = mtile * 16 + i / 160, col = i % 160;
            if (col < 128) uh_out[(size_t)m * 128 + col] = v + U_b[col] + W_b[col];
            else beta_out[(size_t)m * 32 + (col - 128)] = sigmoid_rcp(v + fb_b[col - 128]);
        } else {
            partial[(size_t)blockIdx.x * 2560 + i] = v;
        }
    }
}

// k1b: reduce nsplit partials + bias + activation. grid 2560 x 256.
__global__ __launch_bounds__(256) void k1b_reduce(
    const float* __restrict__ partial,
    const float* __restrict__ U_b, const float* __restrict__ W_b,
    const float* __restrict__ fb_b,
    float* __restrict__ uh_out, float* __restrict__ beta_out, int nsplit)
{
    const int idx = blockIdx.x * 256 + threadIdx.x;   // < 655360
    const int mt = idx / 2560, r = idx % 2560;
    float v = 0.0f;
    for (int s = 0; s < nsplit; s++)
        v += partial[(size_t)(mt * nsplit + s) * 2560 + r];
    const int m = mt * 16 + r / 160, col = r % 160;
    if (col < 128) uh_out[(size_t)m * 128 + col] = v + U_b[col] + W_b[col];
    else beta_out[(size_t)m * 32 + (col - 128)] = sigmoid_rcp(v + fb_b[col - 128]);
}

// ---------------------------------------------------------------------------
// k2: one block (256 thr) per batch. M=p, N=a, K=c. img fp32 in LDS [p][36].
// ---------------------------------------------------------------------------
#define FSTR 36    // floats per LDS row (32 data + 4 pad; 144 B, 16B-aligned)

__global__ __launch_bounds__(256, 4) void k2_attn(
    const float* __restrict__ img,            // [4096][32][196]
    const unsigned short* __restrict__ Whi,   // [128][32]
    const unsigned short* __restrict__ Wlo,
    const float* __restrict__ v_w,            // [128]
    const float* __restrict__ uh,             // [4096][128] (biases folded)
    const float* __restrict__ beta,           // [4096][32]
    float* __restrict__ out)
{
    __shared__ __align__(16) float s_img[208 * FSTR];   // 29952 B
    __shared__ float s_uhv[256];
    __shared__ float s_score[200];
    __shared__ float s_red[8];
    __shared__ float s_ctx[4][32];

    const int tid = threadIdx.x;
    const int b = blockIdx.x;
    const int wave = tid >> 6, lane = tid & 63, quad = lane >> 4, l16 = lane & 15;

    // ---- Phase A: transpose-stage img[b] -> LDS fp32 [p][c] ----
    if (tid < 196) {
        const size_t base = (size_t)b * 6272 + tid;
#pragma unroll
        for (int g = 0; g < 8; g++) {
            floatx4 t;
#pragma unroll
            for (int j = 0; j < 4; j++) t[j] = img[base + (size_t)(4 * g + j) * 196];
            *(floatx4*)&s_img[tid * FSTR + 4 * g] = t;   // ds_write_b128
        }
    } else {
        for (int i = tid - 196; i < 12 * FSTR; i += 60) s_img[196 * FSTR + i] = 0.0f;
    }
    if (tid < 128) s_uhv[tid] = uh[(size_t)b * 128 + tid];
    else s_uhv[tid] = v_w[tid - 128];

    // W frags in regs (L2-hot; launch_bounds(256,4) keeps them resident)
    bf16x8 bh[8], bl[8];
#pragma unroll
    for (int nt = 0; nt < 8; nt++) {
        const int a = nt * 16 + l16;
        bh[nt] = *(const bf16x8*)(Whi + a * 32 + quad * 8);
        bl[nt] = *(const bf16x8*)(Wlo + a * 32 + quad * 8);
    }
    __syncthreads();

    // hoist uh/v values (depend on l16 only) into regs
    float ua[8], va[8];
#pragma unroll
    for (int nt = 0; nt < 8; nt++) {
        ua[nt] = s_uhv[nt * 16 + l16];
        va[nt] = s_uhv[128 + nt * 16 + l16];
    }

    // ---- Phase B: per p-tile: split A-frag from fp32 LDS; 8 nt x 3 mfma ----
    for (int mt = wave; mt < 13; mt += 4) {
        const int p_lane = mt * 16 + l16;
        bf16x8 ah, al;
        split_trunc8(&s_img[p_lane * FSTR + quad * 8], &ah, &al);
        float sc[4] = {0.f, 0.f, 0.f, 0.f};
#pragma unroll
        for (int nt = 0; nt < 8; nt++) {
            floatx4 d = (floatx4)(0.0f);
            d = __builtin_amdgcn_mfma_f32_16x16x32_bf16(ah, bl[nt], d, 0, 0, 0);
            d = __builtin_amdgcn_mfma_f32_16x16x32_bf16(al, bh[nt], d, 0, 0, 0);
            d = __builtin_amdgcn_mfma_f32_16x16x32_bf16(ah, bh[nt], d, 0, 0, 0);
#pragma unroll
            for (int r = 0; r < 4; r++)
                sc[r] = __builtin_fmaf(va[nt], tanh_rcp(d[r] + ua[nt]), sc[r]);
        }
#pragma unroll
        for (int r = 0; r < 4; r++) {
            sc[r] += __shfl_xor(sc[r], 1);
            sc[r] += __shfl_xor(sc[r], 2);
            sc[r] += __shfl_xor(sc[r], 4);
            sc[r] += __shfl_xor(sc[r], 8);
        }
        if (l16 == 0) {
#pragma unroll
            for (int r = 0; r < 4; r++) {
                const int p = mt * 16 + quad * 4 + r;
                if (p < 196) s_score[p] = sc[r];
            }
        }
    }
    __syncthreads();

    // ---- Phase C: softmax over 196 (v_b cancels) ----
    float x = (tid < 196) ? s_score[tid] : -1e30f;
    float m = x;
#pragma unroll
    for (int off = 32; off > 0; off >>= 1) m = fmaxf(m, __shfl_xor(m, off));
    if (lane == 0) s_red[wave] = m;
    __syncthreads();
    m = fmaxf(fmaxf(s_red[0], s_red[1]), fmaxf(s_red[2], s_red[3]));
    float e = (tid < 196) ? __expf(x - m) : 0.0f;
    float ssum = e;
#pragma unroll
    for (int off = 32; off > 0; off >>= 1) ssum += __shfl_xor(ssum, off);
    if (lane == 0) s_red[4 + wave] = ssum;
    __syncthreads();
    const float tot = s_red[4] + s_red[5] + s_red[6] + s_red[7];
    const float wgt = e * __builtin_amdgcn_rcpf(tot);
    if (tid < 196) {
        s_score[tid] = wgt;
        out[131072 + (size_t)b * 196 + tid] = wgt;   // att_weights
    }
    __syncthreads();

    // ---- Phase D: context[c] = beta[c] * sum_p img[p][c]*w[p] (fp32 exact) ----
    {
        const int c = lane & 31;
        const int po = wave * 2 + (lane >> 5);   // 0..7
        float acc = 0.0f;
        for (int j = 0; j < 25; j++) {
            const int p = po + j * 8;
            if (p < 196) acc = __builtin_fmaf(s_img[p * FSTR + c], s_score[p], acc);
        }
        acc += __shfl_xor(acc, 32);
        if ((lane >> 5) == 0) s_ctx[wave][c] = acc;
    }
    __syncthreads();
    if (tid < 32) {
        const float v = s_ctx[0][tid] + s_ctx[1][tid] + s_ctx[2][tid] + s_ctx[3][tid];
        out[(size_t)b * 32 + tid] = v * beta[(size_t)b * 32 + tid];
    }
}

extern "C" void kernel_launch(void* const* d_in, const int* in_sizes, int n_in,
                              void* d_out, int out_size, void* d_ws, size_t ws_size,
                              hipStream_t stream) {
    const float* img    = (const float*)d_in[0];
    const float* hidden = (const float*)d_in[1];
    const float* W_w    = (const float*)d_in[2];
    const float* W_b    = (const float*)d_in[3];
    const float* U_w    = (const float*)d_in[4];
    const float* U_b    = (const float*)d_in[5];
    const float* v_w    = (const float*)d_in[6];
    // d_in[7] = v_b: cancels in softmax
    const float* fb_w   = (const float*)d_in[8];
    const float* fb_b   = (const float*)d_in[9];
    float* out = (float*)d_out;

    float* uh_ws   = (float*)d_ws;                                 // 2 MB
    float* beta_ws = uh_ws + 4096 * 128;                           // 0.5 MB
    unsigned short* Bhi = (unsigned short*)(beta_ws + 4096 * 32);  // 160 KB
    unsigned short* Blo = Bhi + 81920;
    unsigned short* Whi = Blo + 81920;
    unsigned short* Wlo = Whi + 4096;
    float* partial = (float*)(Wlo + 4096);
    const size_t fixed_bytes = ((char*)partial) - ((char*)d_ws);

    // pick split-K factor by available workspace
    int nsplit = 1, direct = 1;
    if (ws_size >= fixed_bytes + (size_t)256 * 4 * 2560 * 4) { nsplit = 4; direct = 0; }
    else if (ws_size >= fixed_bytes + (size_t)256 * 2 * 2560 * 4) { nsplit = 2; direct = 0; }
    else if (ws_size >= fixed_bytes + (size_t)256 * 1 * 2560 * 4) { nsplit = 1; direct = 0; }

    k0_split<<<dim3(336), dim3(256), 0, stream>>>(U_w, fb_w, W_w, Bhi, Blo, Whi, Wlo);
    k1_gemm<<<dim3(256 * nsplit), dim3(256), 0, stream>>>(
        hidden, Bhi, Blo, U_b, W_b, fb_b, uh_ws, beta_ws, partial, nsplit, direct);
    if (!direct)
        k1b_reduce<<<dim3(2560), dim3(256), 0, stream>>>(
            partial, U_b, W_b, fb_b, uh_ws, beta_ws, nsplit);
    k2_attn<<<dim3(4096), dim3(256), 0, stream>>>(img, Whi, Wlo, v_w, uh_ws, beta_ws, out);
}